// Round 3
// baseline (113.285 us; speedup 1.0000x reference)
//
#include <hip/hip_runtime.h>
#include <math.h>

#define DET 512
#define NA  180
#define OUT 362   // floor(sqrt(512^2/2))
#define RAD 181   // OUT/2

#define NSPLIT 3        // angle partitions per (b, tile)
#define APB    60       // angles per block (NA / NSPLIT)
#define CHUNK  10       // angle lines staged per barrier
#define LSTRIDE 516     // line stride in floats

constexpr double PI_D = 3.14159265358979323846;

// ---------------------------------------------------------------------------
// Compile-time trig table (exact-degree symmetry reduction).
// ---------------------------------------------------------------------------
constexpr double tsin(double x) {
    double x2 = x * x;
    return x * (1.0 + x2 * (-1.0/6 + x2 * (1.0/120 + x2 * (-1.0/5040 +
               x2 * (1.0/362880 + x2 * (-1.0/39916800))))));
}
constexpr double tcos(double x) {
    double x2 = x * x;
    return 1.0 + x2 * (-0.5 + x2 * (1.0/24 + x2 * (-1.0/720 +
               x2 * (1.0/40320 + x2 * (-1.0/3628800)))));
}

struct Trig { float c[NA]; float s[NA]; };
constexpr Trig make_trig() {
    Trig t{};
    constexpr double r = PI_D / 180.0;
    for (int k = 0; k < NA; ++k) {
        double c, s;
        if (k <= 45)       { c =  tcos(k * r);          s =  tsin(k * r); }
        else if (k <= 90)  { c =  tsin((90 - k) * r);   s =  tcos((90 - k) * r); }
        else if (k <= 135) { c = -tsin((k - 90) * r);   s =  tcos((k - 90) * r); }
        else               { c = -tcos((180 - k) * r);  s =  tsin((180 - k) * r); }
        t.c[k] = (float)c; t.s[k] = (float)s;
    }
    return t;
}
__device__ constexpr Trig TRIG = make_trig();

// ---------------------------------------------------------------------------
// Ramp-filter weight table for the parity-blocked conv.
// h[0]=0.5, h[m odd]=-2/(pi*m)^2, h[m even!=0]=0.
// Even output d=2e vs odd source s=2i+1:  m = 8u + 2*delta - 1   (half=0)
// Odd  output d=2e+1 vs even source s=2i: m = 8u + 2*delta + 1   (half=1)
// where u = t - i4 (4-blocks), delta = j - l in [-3,3] -> index delta+3.
// ---------------------------------------------------------------------------
struct WTab { float w[2][127][8]; };
constexpr WTab make_wtab() {
    WTab t{};
    for (int h = 0; h < 2; ++h)
        for (int ui = 0; ui < 127; ++ui)
            for (int di = 0; di < 8; ++di) {
                int m = 8 * (ui - 63) + 2 * (di - 3) - 1 + 2 * h;  // always odd
                double md = (double)m;
                t.w[h][ui][di] = (float)(-2.0 / (PI_D * PI_D * md * md));
            }
    return t;
}
__device__ constexpr WTab WTAB = make_wtab();

// ---------------------------------------------------------------------------
// Kernel 1: ramp filter, parity-deinterleaved blocked conv.
// 128 threads: t<64 -> even outputs (sources = odd half), t>=64 -> odd outputs.
// Per u-iteration: 1 ds_read_b128 (lane-varying) + 8 scalar weight loads
// (wave-uniform) feed 16 FMAs. Also zeroes a slice of d_out (for atomics).
// Output layout: ft[b][a][d].
// ---------------------------------------------------------------------------
__global__ __launch_bounds__(128) void ramp_filter_kernel(
        const float* __restrict__ x, float* __restrict__ ft,
        float* __restrict__ out, int n4, int pb4) {
    const int a = blockIdx.x;
    const int b = blockIdx.y;
    const int t = threadIdx.x;   // 0..127

    // --- fold in zeroing of d_out (atomicAdd target) ---
    {
        float4* oz = (float4*)out;
        const float4 z4 = make_float4(0.f, 0.f, 0.f, 0.f);
        const int base4 = (b * NA + a) * pb4;
        for (int i = t; i < pb4; i += 128) {
            int idx = base4 + i;
            if (idx < n4) oz[idx] = z4;
        }
    }

    __shared__ float Ef[768];   // even samples, 64 zero-float4s pad each side
    __shared__ float Of[768];   // odd samples, same padding

    const float2 z2 = make_float2(0.f, 0.f);
    *(float2*)&Ef[2 * t]       = z2;
    *(float2*)&Ef[512 + 2 * t] = z2;
    *(float2*)&Of[2 * t]       = z2;
    *(float2*)&Of[512 + 2 * t] = z2;

    // x is (B,1,DET,NA): column (b,:,a); deinterleave by parity
    const float* xc = x + (size_t)(b * DET) * NA + a;
    float v0 = xc[(4 * t + 0) * NA];
    float v1 = xc[(4 * t + 1) * NA];
    float v2 = xc[(4 * t + 2) * NA];
    float v3 = xc[(4 * t + 3) * NA];
    *(float2*)&Ef[256 + 2 * t] = make_float2(v0, v2);
    *(float2*)&Of[256 + 2 * t] = make_float2(v1, v3);
    __syncthreads();

    const int half = t >> 6;    // wave-uniform (wave size 64)
    const int tp   = t & 63;
    const float4* src4  = (const float4*)(half ? Ef : Of);  // opposite parity
    const float4* self4 = (const float4*)(half ? Of : Ef);

    float acc0 = 0.f, acc1 = 0.f, acc2 = 0.f, acc3 = 0.f;
    #pragma unroll 4
    for (int ui = 0; ui < 127; ++ui) {
        const float* __restrict__ w = WTAB.w[half][ui];   // wave-uniform -> SGPR
        float4 s4 = src4[tp + (127 - ui)];                 // i4 = tp - u, u=ui-63
        acc0 = fmaf(s4.x, w[3], fmaf(s4.y, w[2], fmaf(s4.z, w[1], fmaf(s4.w, w[0], acc0))));
        acc1 = fmaf(s4.x, w[4], fmaf(s4.y, w[3], fmaf(s4.z, w[2], fmaf(s4.w, w[1], acc1))));
        acc2 = fmaf(s4.x, w[5], fmaf(s4.y, w[4], fmaf(s4.z, w[3], fmaf(s4.w, w[2], acc2))));
        acc3 = fmaf(s4.x, w[6], fmaf(s4.y, w[5], fmaf(s4.z, w[4], fmaf(s4.w, w[3], acc3))));
    }

    // self term: 0.5 * x[d]
    float4 sf = self4[64 + tp];
    acc0 = fmaf(0.5f, sf.x, acc0);
    acc1 = fmaf(0.5f, sf.y, acc1);
    acc2 = fmaf(0.5f, sf.z, acc2);
    acc3 = fmaf(0.5f, sf.w, acc3);

    // outputs d = 8*tp + 2*j + half
    float* o = ft + (b * NA + a) * DET + 8 * tp + half;
    o[0] = acc0;
    o[2] = acc1;
    o[4] = acc2;
    o[6] = acc3;
}

// ---------------------------------------------------------------------------
// Kernel 2: backprojection (unchanged from R2).
// ---------------------------------------------------------------------------
__device__ __forceinline__ float interp1(const float* __restrict__ L, float pos) {
    float pf = floorf(pos);
    int   i0 = (int)pf;
    float fr = pos - pf;
    float g0 = L[i0];
    float g1 = L[i0 + 1];          // L[512] is a zero sentinel
    float v  = fmaf(fr, g1 - g0, g0);
    return pos <= (float)(DET - 1) ? v : 0.0f;
}

__global__ __launch_bounds__(256) void backproject_kernel(
        const float* __restrict__ ft, float* __restrict__ out) {
    const int bz = blockIdx.z;
    const int b  = bz / NSPLIT;
    const int sp = bz - b * NSPLIT;
    const int r0 = blockIdx.y * 32;
    const int c0 = blockIdx.x * 32;
    const int tid = threadIdx.x;
    const int tx = tid & 15;
    const int ty = tid >> 4;

    __shared__ float line[CHUNK * LSTRIDE];

    if (tid < CHUNK) line[tid * LSTRIDE + 512] = 0.0f;   // zero sentinels

    const float xpr = (float)(min(r0 + ty, OUT - 1) - RAD);
    const float ypr = (float)(min(c0 + tx, OUT - 1) - RAD);

    float a00 = 0.0f, a01 = 0.0f, a10 = 0.0f, a11 = 0.0f;

    const float* base = ft + (b * NA + sp * APB) * DET;

    for (int rd = 0; rd < APB / CHUNK; ++rd) {
        __syncthreads();
        const float4* g = (const float4*)(base + rd * CHUNK * DET);
        #pragma unroll
        for (int k = 0; k < (CHUNK * DET / 4) / 256; ++k) {
            int j4 = tid + k * 256;
            float4 v = g[j4];
            int c = j4 >> 7;
            int d = (j4 & 127) << 2;
            *(float4*)&line[c * LSTRIDE + d] = v;
        }
        __syncthreads();

        const int abase = sp * APB + rd * CHUNK;
        #pragma unroll
        for (int i = 0; i < CHUNK; ++i) {
            const float cv = TRIG.c[abase + i];
            const float sv = TRIG.s[abase + i];
            float p00 = fmaf(ypr, cv, fmaf(xpr, -sv, 256.0f));
            float p01 = fmaf(16.0f, cv, p00);
            float p10 = fmaf(-16.0f, sv, p00);
            float p11 = fmaf(-16.0f, sv, p01);
            const float* L = line + i * LSTRIDE;
            a00 += interp1(L, p00);
            a01 += interp1(L, p01);
            a10 += interp1(L, p10);
            a11 += interp1(L, p11);
        }
    }

    const float scale = (float)(PI_D / (2.0 * NA));
    const int r = r0 + ty;
    const int c = c0 + tx;
    float* ob = out + b * OUT * OUT;
    if (r < OUT) {
        if (c < OUT)      atomicAdd(&ob[r * OUT + c],      a00 * scale);
        if (c + 16 < OUT) atomicAdd(&ob[r * OUT + c + 16], a01 * scale);
    }
    if (r + 16 < OUT) {
        if (c < OUT)      atomicAdd(&ob[(r + 16) * OUT + c],      a10 * scale);
        if (c + 16 < OUT) atomicAdd(&ob[(r + 16) * OUT + c + 16], a11 * scale);
    }
}

extern "C" void kernel_launch(void* const* d_in, const int* in_sizes, int n_in,
                              void* d_out, int out_size, void* d_ws, size_t ws_size,
                              hipStream_t stream) {
    const float* x = (const float*)d_in[0];
    float* ft  = (float*)d_ws;     // B*NA*DET*4 = 1.47 MB scratch
    float* out = (float*)d_out;

    const int B = in_sizes[0] / (DET * NA);   // 4

    const int n4  = out_size / 4;                       // float4 count (divisible)
    const int pb4 = (n4 + NA * B - 1) / (NA * B);       // float4s zeroed per block

    ramp_filter_kernel<<<dim3(NA, B), 128, 0, stream>>>(x, ft, out, n4, pb4);
    backproject_kernel<<<dim3((OUT + 31) / 32, (OUT + 31) / 32, B * NSPLIT),
                         256, 0, stream>>>(ft, out);
}